// Round 3
// baseline (9692.372 us; speedup 1.0000x reference)
//
#include <hip/hip_runtime.h>
#include <math.h>

#define BB 32
#define TT 512
#define FF 1024
#define UU 1024
#define NBLK 64

typedef __attribute__((ext_vector_type(8))) short s8v;    // 8 x bf16 (4 VGPR)
typedef __attribute__((ext_vector_type(4))) float f4v;    // 4 x f32

static __device__ __forceinline__ unsigned short f2bf(float f) {
    unsigned int u = __builtin_bit_cast(unsigned int, f);
    u += 0x7fff + ((u >> 16) & 1);          // RNE
    return (unsigned short)(u >> 16);
}
static __device__ __forceinline__ float bf2f(unsigned short b) {
    unsigned int u = ((unsigned int)b) << 16;
    return __builtin_bit_cast(float, u);
}

// ---------------------------------------------------------------------------
// fp32 -> bf16 elementwise (vectorized, 4/thread)
// ---------------------------------------------------------------------------
__global__ __launch_bounds__(256) void cvt_bf16(
    const float* __restrict__ in, unsigned short* __restrict__ out, int n4)
{
    int i = blockIdx.x * 256 + threadIdx.x;
    if (i < n4) {
        float4 v = ((const float4*)in)[i];
        ushort4 o;
        o.x = f2bf(v.x); o.y = f2bf(v.y); o.z = f2bf(v.z); o.w = f2bf(v.w);
        ((ushort4*)out)[i] = o;
    }
}

// ---------------------------------------------------------------------------
// Transpose + convert: W [ROWS k][COLS n] f32 -> WT [COLS][ROWS] bf16
// ---------------------------------------------------------------------------
template<int ROWS, int COLS>
__global__ __launch_bounds__(256) void transpose_bf16(
    const float* __restrict__ W, unsigned short* __restrict__ WT)
{
    __shared__ float tl[32][33];
    const int tx = threadIdx.x, ty = threadIdx.y;   // block (32, 8)
    const int bx = blockIdx.x, by = blockIdx.y;
    #pragma unroll
    for (int i = 0; i < 4; ++i) {
        int r = by * 32 + ty + i * 8;
        int c = bx * 32 + tx;
        tl[ty + i * 8][tx] = W[(size_t)r * COLS + c];
    }
    __syncthreads();
    #pragma unroll
    for (int i = 0; i < 4; ++i) {
        int n = bx * 32 + ty + i * 8;
        int k = by * 32 + tx;
        WT[(size_t)n * ROWS + k] = f2bf(tl[tx][ty + i * 8]);
    }
}

// ---------------------------------------------------------------------------
// Precompute GEMM: C[M,N] bf16 = A[M,1024] bf16 @ B, with B given transposed
// as BT[N][2048] (only k = 0..1023 used).  128x128 tile, 4 waves, 16x16x32.
// ---------------------------------------------------------------------------
__global__ __launch_bounds__(256) void gemm_xproj(
    const unsigned short* __restrict__ A,    // [M][1024]
    const unsigned short* __restrict__ BT,   // [N][2048]
    unsigned short* __restrict__ C,          // [M][N]
    int N)
{
    __shared__ unsigned short Al[128][72];
    __shared__ unsigned short Bl[128][72];
    const int tid  = threadIdx.x;
    const int lane = tid & 63;
    const int wave = tid >> 6;
    const int l15  = lane & 15;
    const int kg   = lane >> 4;
    const int m0   = blockIdx.y * 128;
    const int n0   = blockIdx.x * 128;
    const int rowOff = (wave >> 1) * 64;
    const int colOff = (wave & 1) * 64;

    f4v acc[4][4];
    #pragma unroll
    for (int m = 0; m < 4; ++m)
        #pragma unroll
        for (int n = 0; n < 4; ++n) acc[m][n] = (f4v){0.f, 0.f, 0.f, 0.f};

    for (int k0 = 0; k0 < 1024; k0 += 64) {
        #pragma unroll
        for (int it = 0; it < 4; ++it) {
            int c = tid + it * 256;
            int r = c >> 3, off = (c & 7) * 8;
            *(s8v*)&Al[r][off] = *(const s8v*)(A + (size_t)(m0 + r) * 1024 + k0 + off);
            *(s8v*)&Bl[r][off] = *(const s8v*)(BT + (size_t)(n0 + r) * 2048 + k0 + off);
        }
        __syncthreads();
        #pragma unroll
        for (int ks = 0; ks < 2; ++ks) {
            s8v a[4], b[4];
            #pragma unroll
            for (int m = 0; m < 4; ++m)
                a[m] = *(const s8v*)&Al[rowOff + m * 16 + l15][ks * 32 + kg * 8];
            #pragma unroll
            for (int n = 0; n < 4; ++n)
                b[n] = *(const s8v*)&Bl[colOff + n * 16 + l15][ks * 32 + kg * 8];
            #pragma unroll
            for (int m = 0; m < 4; ++m)
                #pragma unroll
                for (int n = 0; n < 4; ++n)
                    acc[m][n] = __builtin_amdgcn_mfma_f32_16x16x32_bf16(a[m], b[n], acc[m][n], 0, 0, 0);
        }
        __syncthreads();
    }
    #pragma unroll
    for (int m = 0; m < 4; ++m)
        #pragma unroll
        for (int n = 0; n < 4; ++n)
            #pragma unroll
            for (int i = 0; i < 4; ++i) {
                int row = m0 + rowOff + m * 16 + kg * 4 + i;
                int col = n0 + colOff + n * 16 + l15;
                C[(size_t)row * N + col] = f2bf(acc[m][n][i]);
            }
}

// ---------------------------------------------------------------------------
// Persistent GRU recurrence. 64 blocks x 256 threads, all co-resident.
// Block i owns gate cols [i*32, i*32+32) and cand cols [i*16, i*16+16).
// Recurrent weight B-fragments live in registers for the whole kernel.
// Two device-scope grid barriers per step.
// ---------------------------------------------------------------------------
__device__ __forceinline__ void grid_barrier(unsigned* counter, unsigned* gen,
                                             unsigned epoch, int tid)
{
    __syncthreads();
    if (tid == 0) {
        __threadfence();
        unsigned arrived = __hip_atomic_fetch_add(counter, 1u, __ATOMIC_ACQ_REL,
                                                  __HIP_MEMORY_SCOPE_AGENT);
        if (arrived == NBLK - 1) {
            __hip_atomic_store(counter, 0u, __ATOMIC_RELAXED, __HIP_MEMORY_SCOPE_AGENT);
            __hip_atomic_store(gen, epoch, __ATOMIC_RELEASE, __HIP_MEMORY_SCOPE_AGENT);
        } else {
            while (__hip_atomic_load(gen, __ATOMIC_ACQUIRE, __HIP_MEMORY_SCOPE_AGENT) < epoch)
                __builtin_amdgcn_s_sleep(1);
        }
    }
    __syncthreads();
}

__global__ __launch_bounds__(256, 1) void gru_persistent(
    const unsigned short* __restrict__ WgT,   // [2048][2048] bf16
    const unsigned short* __restrict__ WcT,   // [1024][2048] bf16
    const unsigned short* __restrict__ Xgb,   // [B*T][2048] bf16
    const unsigned short* __restrict__ Xcb,   // [B*T][1024] bf16
    const float* __restrict__ bg,             // [2048]
    const float* __restrict__ bc,             // [1024]
    float* __restrict__ h,                    // [32][1024] f32
    unsigned short* __restrict__ hb,          // [32][1024] bf16
    unsigned short* __restrict__ rhb,         // [32][1024] bf16
    float* __restrict__ ub,                   // [32][1024] f32
    float* __restrict__ out,                  // [B][T][U] f32
    unsigned* __restrict__ bar)               // [2]: counter, gen
{
    __shared__ float red[4][32][32];          // 16 KB; reused as [4][32][16] in C
    const int tid  = threadIdx.x;
    const int lane = tid & 63;
    const int wave = tid >> 6;
    const int l15  = lane & 15;
    const int kg   = lane >> 4;
    const int blk  = blockIdx.x;
    const int gj0  = blk * 32;                // gate column base
    const int cj0  = blk * 16;                // cand column base
    const int kb   = wave * 256;              // recurrent k-slice base
    const bool is_r = (gj0 < UU);             // blocks 0..31 produce r, 32..63 produce u

    // ---- load recurrent weight B-fragments into registers (once) ----
    s8v bgf[2][8], bcf[8];
    #pragma unroll
    for (int n = 0; n < 2; ++n)
        #pragma unroll
        for (int kk = 0; kk < 8; ++kk)
            bgf[n][kk] = *(const s8v*)(WgT + (size_t)(gj0 + n * 16 + l15) * 2048
                                            + 1024 + kb + kk * 32 + kg * 8);
    #pragma unroll
    for (int kk = 0; kk < 8; ++kk)
        bcf[kk] = *(const s8v*)(WcT + (size_t)(cj0 + l15) * 2048
                                     + 1024 + kb + kk * 32 + kg * 8);

    // epilogue mapping: thread -> (batch, col-group)
    const int eb = tid >> 3;                  // 0..31
    const int eq = tid & 7;                   // 0..7
    const float4 bgv = *(const float4*)(bg + gj0 + eq * 4);
    const float2 bcv = *(const float2*)(bc + cj0 + eq * 2);

    unsigned* counter = bar;
    unsigned* gen     = bar + 1;
    unsigned epoch = 0;

    for (int t = 0; t < TT; ++t) {
        // ================= phase G: gates =================
        // early-issue epilogue operands
        ushort4 xg = *(const ushort4*)(Xgb + ((size_t)eb * TT + t) * 2048 + gj0 + eq * 4);
        float4 hsl;
        if (is_r) hsl = *(const float4*)(h + eb * UU + gj0 + eq * 4);

        // A-fragments from hb (full K slice for this wave)
        s8v a[2][8];
        #pragma unroll
        for (int m = 0; m < 2; ++m)
            #pragma unroll
            for (int kk = 0; kk < 8; ++kk)
                a[m][kk] = *(const s8v*)(hb + (size_t)(m * 16 + l15) * 1024 + kb + kk * 32 + kg * 8);

        f4v acc[2][2];
        #pragma unroll
        for (int m = 0; m < 2; ++m)
            #pragma unroll
            for (int n = 0; n < 2; ++n) acc[m][n] = (f4v){0.f, 0.f, 0.f, 0.f};
        #pragma unroll
        for (int kk = 0; kk < 8; ++kk)
            #pragma unroll
            for (int m = 0; m < 2; ++m)
                #pragma unroll
                for (int n = 0; n < 2; ++n)
                    acc[m][n] = __builtin_amdgcn_mfma_f32_16x16x32_bf16(a[m][kk], bgf[n][kk], acc[m][n], 0, 0, 0);

        #pragma unroll
        for (int m = 0; m < 2; ++m)
            #pragma unroll
            for (int n = 0; n < 2; ++n)
                #pragma unroll
                for (int i = 0; i < 4; ++i)
                    red[wave][m * 16 + kg * 4 + i][n * 16 + l15] = acc[m][n][i];
        __syncthreads();

        f4v pre = *(const f4v*)&red[0][eb][eq * 4];
        #pragma unroll
        for (int w = 1; w < 4; ++w) pre += *(const f4v*)&red[w][eb][eq * 4];
        pre[0] += bf2f(xg.x) + bgv.x;
        pre[1] += bf2f(xg.y) + bgv.y;
        pre[2] += bf2f(xg.z) + bgv.z;
        pre[3] += bf2f(xg.w) + bgv.w;
        float s0 = 1.f / (1.f + __expf(-pre[0]));
        float s1 = 1.f / (1.f + __expf(-pre[1]));
        float s2 = 1.f / (1.f + __expf(-pre[2]));
        float s3 = 1.f / (1.f + __expf(-pre[3]));
        if (is_r) {
            ushort4 o;
            o.x = f2bf(s0 * hsl.x); o.y = f2bf(s1 * hsl.y);
            o.z = f2bf(s2 * hsl.z); o.w = f2bf(s3 * hsl.w);
            *(ushort4*)(rhb + eb * UU + gj0 + eq * 4) = o;
        } else {
            float4 uo = {s0, s1, s2, s3};
            *(float4*)(ub + eb * UU + (gj0 - UU) + eq * 4) = uo;
        }
        ++epoch;
        grid_barrier(counter, gen, epoch, tid);

        // ================= phase C: candidate + update =================
        ushort2 xc = *(const ushort2*)(Xcb + ((size_t)eb * TT + t) * 1024 + cj0 + eq * 2);
        float2 uv  = *(const float2*)(ub + eb * UU + cj0 + eq * 2);
        float2 hv  = *(const float2*)(h  + eb * UU + cj0 + eq * 2);

        s8v ac[2][8];
        #pragma unroll
        for (int m = 0; m < 2; ++m)
            #pragma unroll
            for (int kk = 0; kk < 8; ++kk)
                ac[m][kk] = *(const s8v*)(rhb + (size_t)(m * 16 + l15) * 1024 + kb + kk * 32 + kg * 8);

        f4v acc2[2];
        acc2[0] = (f4v){0.f, 0.f, 0.f, 0.f};
        acc2[1] = (f4v){0.f, 0.f, 0.f, 0.f};
        #pragma unroll
        for (int kk = 0; kk < 8; ++kk)
            #pragma unroll
            for (int m = 0; m < 2; ++m)
                acc2[m] = __builtin_amdgcn_mfma_f32_16x16x32_bf16(ac[m][kk], bcf[kk], acc2[m], 0, 0, 0);

        float* redc = (float*)red;            // [4][32][16]
        __syncthreads();                      // ensure phase-G reduce reads done
        #pragma unroll
        for (int m = 0; m < 2; ++m)
            #pragma unroll
            for (int i = 0; i < 4; ++i)
                redc[((size_t)wave * 32 + m * 16 + kg * 4 + i) * 16 + l15] = acc2[m][i];
        __syncthreads();

        float2 pre2 = *(const float2*)&redc[(0 * 32 + eb) * 16 + eq * 2];
        #pragma unroll
        for (int w = 1; w < 4; ++w) {
            float2 p = *(const float2*)&redc[((size_t)w * 32 + eb) * 16 + eq * 2];
            pre2.x += p.x; pre2.y += p.y;
        }
        float c0 = pre2.x + bf2f(xc.x) + bcv.x;
        float c1 = pre2.y + bf2f(xc.y) + bcv.y;
        c0 = fminf(fmaxf(c0, -15.f), 15.f);
        c1 = fminf(fmaxf(c1, -15.f), 15.f);
        float e0 = __expf(2.f * c0), e1 = __expf(2.f * c1);
        float t0 = (e0 - 1.f) / (e0 + 1.f);
        float t1 = (e1 - 1.f) / (e1 + 1.f);
        float hn0 = uv.x * hv.x + (1.f - uv.x) * t0;
        float hn1 = uv.y * hv.y + (1.f - uv.y) * t1;

        *(float2*)(h + eb * UU + cj0 + eq * 2) = make_float2(hn0, hn1);
        ushort2 hbo; hbo.x = f2bf(hn0); hbo.y = f2bf(hn1);
        *(ushort2*)(hb + eb * UU + cj0 + eq * 2) = hbo;
        *(float2*)(out + ((size_t)eb * TT + t) * UU + cj0 + eq * 2) = make_float2(hn0, hn1);

        ++epoch;
        grid_barrier(counter, gen, epoch, tid);
    }
}

// ===========================================================================
// Fallback per-step kernels (round-2, verified) — used only if ws too small.
// ===========================================================================
__global__ __launch_bounds__(256) void gru_gates2(
    const unsigned short* __restrict__ hb, const unsigned short* __restrict__ WgT,
    const unsigned short* __restrict__ Xgb, const float* __restrict__ bg,
    const float* __restrict__ h, unsigned short* __restrict__ rhb,
    float* __restrict__ ubuf, int t)
{
    __shared__ unsigned short hb_l[32][1032];
    __shared__ unsigned short Wl[16][1032];
    __shared__ float red[4][32][16];
    const int tid = threadIdx.x, lane = tid & 63, wave = tid >> 6;
    const int l15 = lane & 15, kg = lane >> 4;
    const int j0 = blockIdx.x * 16;
    #pragma unroll
    for (int it = 0; it < 16; ++it) {
        int c = tid + it * 256; int r = c >> 7, off = (c & 127) * 8;
        *(s8v*)&hb_l[r][off] = *(const s8v*)(hb + (size_t)r * 1024 + off);
    }
    #pragma unroll
    for (int it = 0; it < 8; ++it) {
        int c = tid + it * 256; int r = c >> 7, off = (c & 127) * 8;
        *(s8v*)&Wl[r][off] = *(const s8v*)(WgT + (size_t)(j0 + r) * 2048 + 1024 + off);
    }
    __syncthreads();
    f4v acc0 = (f4v){0.f,0.f,0.f,0.f}, acc1 = (f4v){0.f,0.f,0.f,0.f};
    const int kbase = wave * 256;
    #pragma unroll
    for (int kk = 0; kk < 8; ++kk) {
        int k = kbase + kk * 32 + kg * 8;
        s8v a0 = *(const s8v*)&hb_l[l15][k];
        s8v a1 = *(const s8v*)&hb_l[16 + l15][k];
        s8v b  = *(const s8v*)&Wl[l15][k];
        acc0 = __builtin_amdgcn_mfma_f32_16x16x32_bf16(a0, b, acc0, 0, 0, 0);
        acc1 = __builtin_amdgcn_mfma_f32_16x16x32_bf16(a1, b, acc1, 0, 0, 0);
    }
    #pragma unroll
    for (int i = 0; i < 4; ++i) {
        red[wave][kg * 4 + i][l15] = acc0[i];
        red[wave][16 + kg * 4 + i][l15] = acc1[i];
    }
    __syncthreads();
    for (int e = tid; e < 512; e += 256) {
        int b = e >> 4, col = e & 15;
        int j = j0 + col;
        float pre = red[0][b][col] + red[1][b][col] + red[2][b][col] + red[3][b][col];
        pre += bf2f(Xgb[((size_t)b * TT + t) * 2048 + j]) + bg[j];
        float s = 1.f / (1.f + __expf(-pre));
        if (j < UU) rhb[b * UU + j] = f2bf(s * h[b * UU + j]);
        else        ubuf[b * UU + (j - UU)] = s;
    }
}

__global__ __launch_bounds__(256) void gru_cand2(
    const unsigned short* __restrict__ rhb, const unsigned short* __restrict__ WcT,
    const unsigned short* __restrict__ Xcb, const float* __restrict__ bc,
    const float* __restrict__ ubuf, float* __restrict__ h,
    unsigned short* __restrict__ hb, float* __restrict__ out, int t)
{
    __shared__ unsigned short rh_l[32][1032];
    __shared__ unsigned short Wl[16][1032];
    __shared__ float red[4][32][16];
    const int tid = threadIdx.x, lane = tid & 63, wave = tid >> 6;
    const int l15 = lane & 15, kg = lane >> 4;
    const int j0 = blockIdx.x * 16;
    #pragma unroll
    for (int it = 0; it < 16; ++it) {
        int c = tid + it * 256; int r = c >> 7, off = (c & 127) * 8;
        *(s8v*)&rh_l[r][off] = *(const s8v*)(rhb + (size_t)r * 1024 + off);
    }
    #pragma unroll
    for (int it = 0; it < 8; ++it) {
        int c = tid + it * 256; int r = c >> 7, off = (c & 127) * 8;
        *(s8v*)&Wl[r][off] = *(const s8v*)(WcT + (size_t)(j0 + r) * 2048 + 1024 + off);
    }
    __syncthreads();
    f4v acc0 = (f4v){0.f,0.f,0.f,0.f}, acc1 = (f4v){0.f,0.f,0.f,0.f};
    const int kbase = wave * 256;
    #pragma unroll
    for (int kk = 0; kk < 8; ++kk) {
        int k = kbase + kk * 32 + kg * 8;
        s8v a0 = *(const s8v*)&rh_l[l15][k];
        s8v a1 = *(const s8v*)&rh_l[16 + l15][k];
        s8v b  = *(const s8v*)&Wl[l15][k];
        acc0 = __builtin_amdgcn_mfma_f32_16x16x32_bf16(a0, b, acc0, 0, 0, 0);
        acc1 = __builtin_amdgcn_mfma_f32_16x16x32_bf16(a1, b, acc1, 0, 0, 0);
    }
    #pragma unroll
    for (int i = 0; i < 4; ++i) {
        red[wave][kg * 4 + i][l15] = acc0[i];
        red[wave][16 + kg * 4 + i][l15] = acc1[i];
    }
    __syncthreads();
    for (int e = tid; e < 512; e += 256) {
        int b = e >> 4, col = e & 15;
        int j = j0 + col;
        float pre = red[0][b][col] + red[1][b][col] + red[2][b][col] + red[3][b][col];
        pre += bf2f(Xcb[((size_t)b * TT + t) * 1024 + j]) + bc[j];
        float cv = tanhf(pre);
        float u  = ubuf[b * UU + j];
        float hv = h[b * UU + j];
        float hn = u * hv + (1.f - u) * cv;
        h[b * UU + j]  = hn;
        hb[b * UU + j] = f2bf(hn);
        out[((size_t)b * TT + t) * UU + j] = hn;
    }
}

// ===========================================================================
extern "C" void kernel_launch(void* const* d_in, const int* in_sizes, int n_in,
                              void* d_out, int out_size, void* d_ws, size_t ws_size,
                              hipStream_t stream) {
    const float* x  = (const float*)d_in[0];
    const float* Wg = (const float*)d_in[1];
    const float* bg = (const float*)d_in[2];
    const float* Wc = (const float*)d_in[3];
    const float* bc = (const float*)d_in[4];
    float* out = (float*)d_out;

    const size_t XB_B  = (size_t)BB * TT * FF * 2;
    const size_t WGT_B = (size_t)2 * UU * (FF + UU) * 2;
    const size_t WCT_B = (size_t)UU * (FF + UU) * 2;
    const size_t XG_B  = (size_t)BB * TT * 2 * UU * 2;
    const size_t XC_B  = (size_t)BB * TT * UU * 2;
    const size_t H_B   = (size_t)BB * UU * 4;
    const size_t HB_B  = (size_t)BB * UU * 2;
    const size_t BAR_B = 256;
    const size_t NEED  = XB_B + WGT_B + WCT_B + XG_B + XC_B + H_B + HB_B * 2 + H_B + BAR_B;

    char* p = (char*)d_ws;
    unsigned short* xb  = (unsigned short*)p;            p += XB_B;
    unsigned short* WgT = (unsigned short*)p;            p += WGT_B;
    unsigned short* WcT = (unsigned short*)p;            p += WCT_B;
    unsigned short* Xgb = (unsigned short*)p;            p += XG_B;
    unsigned short* Xcb = (unsigned short*)p;            p += XC_B;
    float*          h   = (float*)p;                     p += H_B;
    unsigned short* hb  = (unsigned short*)p;            p += HB_B;
    unsigned short* rhb = (unsigned short*)p;            p += HB_B;
    float*          ub  = (float*)p;                     p += H_B;
    unsigned*       bar = (unsigned*)p;                  p += BAR_B;

    // ---- one-time prep ----
    cvt_bf16<<<(BB * TT * FF / 4 + 255) / 256, 256, 0, stream>>>(x, xb, BB * TT * FF / 4);
    transpose_bf16<FF + UU, 2 * UU><<<dim3(64, 64), dim3(32, 8), 0, stream>>>(Wg, WgT);
    transpose_bf16<FF + UU, UU>    <<<dim3(32, 64), dim3(32, 8), 0, stream>>>(Wc, WcT);
    gemm_xproj<<<dim3(2 * UU / 128, BB * TT / 128), 256, 0, stream>>>(xb, WgT, Xgb, 2 * UU);
    gemm_xproj<<<dim3(UU / 128,     BB * TT / 128), 256, 0, stream>>>(xb, WcT, Xcb, UU);
    hipMemsetAsync(h,   0, H_B,   stream);
    hipMemsetAsync(hb,  0, HB_B,  stream);
    hipMemsetAsync(bar, 0, BAR_B, stream);

    if (ws_size >= NEED) {
        gru_persistent<<<NBLK, 256, 0, stream>>>(WgT, WcT, Xgb, Xcb, bg, bc,
                                                 h, hb, rhb, ub, out, bar);
    } else {
        for (int t = 0; t < TT; ++t) {
            gru_gates2<<<128, 256, 0, stream>>>(hb, WgT, Xgb, bg, h, rhb, ub, t);
            gru_cand2 <<< 64, 256, 0, stream>>>(rhb, WcT, Xcb, bc, ub, h, hb, out, t);
        }
    }
}

// Round 4
// 7737.971 us; speedup vs baseline: 1.2526x; 1.2526x over previous
//
#include <hip/hip_runtime.h>
#include <math.h>

#define BB 32
#define TT 512
#define FF 1024
#define UU 1024
#define NBLK 64

typedef __attribute__((ext_vector_type(8))) short s8v;    // 8 x bf16 (4 VGPR)
typedef __attribute__((ext_vector_type(4))) float f4v;    // 4 x f32

static __device__ __forceinline__ unsigned short f2bf(float f) {
    unsigned int u = __builtin_bit_cast(unsigned int, f);
    u += 0x7fff + ((u >> 16) & 1);          // RNE
    return (unsigned short)(u >> 16);
}
static __device__ __forceinline__ float bf2f(unsigned short b) {
    unsigned int u = ((unsigned int)b) << 16;
    return __builtin_bit_cast(float, u);
}

// ---------------------------------------------------------------------------
__global__ __launch_bounds__(256) void cvt_bf16(
    const float* __restrict__ in, unsigned short* __restrict__ out, int n4)
{
    int i = blockIdx.x * 256 + threadIdx.x;
    if (i < n4) {
        float4 v = ((const float4*)in)[i];
        ushort4 o;
        o.x = f2bf(v.x); o.y = f2bf(v.y); o.z = f2bf(v.z); o.w = f2bf(v.w);
        ((ushort4*)out)[i] = o;
    }
}

// ---------------------------------------------------------------------------
template<int ROWS, int COLS>
__global__ __launch_bounds__(256) void transpose_bf16(
    const float* __restrict__ W, unsigned short* __restrict__ WT)
{
    __shared__ float tl[32][33];
    const int tx = threadIdx.x, ty = threadIdx.y;   // block (32, 8)
    const int bx = blockIdx.x, by = blockIdx.y;
    #pragma unroll
    for (int i = 0; i < 4; ++i) {
        int r = by * 32 + ty + i * 8;
        int c = bx * 32 + tx;
        tl[ty + i * 8][tx] = W[(size_t)r * COLS + c];
    }
    __syncthreads();
    #pragma unroll
    for (int i = 0; i < 4; ++i) {
        int n = bx * 32 + ty + i * 8;
        int k = by * 32 + tx;
        WT[(size_t)n * ROWS + k] = f2bf(tl[tx][ty + i * 8]);
    }
}

// ---------------------------------------------------------------------------
__global__ __launch_bounds__(256) void gemm_xproj(
    const unsigned short* __restrict__ A,    // [M][1024]
    const unsigned short* __restrict__ BT,   // [N][2048]
    unsigned short* __restrict__ C,          // [M][N]
    int N)
{
    __shared__ unsigned short Al[128][72];
    __shared__ unsigned short Bl[128][72];
    const int tid  = threadIdx.x;
    const int lane = tid & 63;
    const int wave = tid >> 6;
    const int l15  = lane & 15;
    const int kg   = lane >> 4;
    const int m0   = blockIdx.y * 128;
    const int n0   = blockIdx.x * 128;
    const int rowOff = (wave >> 1) * 64;
    const int colOff = (wave & 1) * 64;

    f4v acc[4][4];
    #pragma unroll
    for (int m = 0; m < 4; ++m)
        #pragma unroll
        for (int n = 0; n < 4; ++n) acc[m][n] = (f4v){0.f, 0.f, 0.f, 0.f};

    for (int k0 = 0; k0 < 1024; k0 += 64) {
        #pragma unroll
        for (int it = 0; it < 4; ++it) {
            int c = tid + it * 256;
            int r = c >> 3, off = (c & 7) * 8;
            *(s8v*)&Al[r][off] = *(const s8v*)(A + (size_t)(m0 + r) * 1024 + k0 + off);
            *(s8v*)&Bl[r][off] = *(const s8v*)(BT + (size_t)(n0 + r) * 2048 + k0 + off);
        }
        __syncthreads();
        #pragma unroll
        for (int ks = 0; ks < 2; ++ks) {
            s8v a[4], b[4];
            #pragma unroll
            for (int m = 0; m < 4; ++m)
                a[m] = *(const s8v*)&Al[rowOff + m * 16 + l15][ks * 32 + kg * 8];
            #pragma unroll
            for (int n = 0; n < 4; ++n)
                b[n] = *(const s8v*)&Bl[colOff + n * 16 + l15][ks * 32 + kg * 8];
            #pragma unroll
            for (int m = 0; m < 4; ++m)
                #pragma unroll
                for (int n = 0; n < 4; ++n)
                    acc[m][n] = __builtin_amdgcn_mfma_f32_16x16x32_bf16(a[m], b[n], acc[m][n], 0, 0, 0);
        }
        __syncthreads();
    }
    #pragma unroll
    for (int m = 0; m < 4; ++m)
        #pragma unroll
        for (int n = 0; n < 4; ++n)
            #pragma unroll
            for (int i = 0; i < 4; ++i) {
                int row = m0 + rowOff + m * 16 + kg * 4 + i;
                int col = n0 + colOff + n * 16 + l15;
                C[(size_t)row * N + col] = f2bf(acc[m][n][i]);
            }
}

// ---------------------------------------------------------------------------
// Relaxed-spin grid barrier: one wb + one inv per block per barrier.
// Monotonic counter (no reset race); target = epoch * NBLK.
// ---------------------------------------------------------------------------
__device__ __forceinline__ void grid_barrier(unsigned* counter, unsigned target, int tid)
{
    __syncthreads();
    if (tid == 0) {
        __builtin_amdgcn_fence(__ATOMIC_RELEASE, "agent");       // publish (once)
        __hip_atomic_fetch_add(counter, 1u, __ATOMIC_RELAXED, __HIP_MEMORY_SCOPE_AGENT);
        while (__hip_atomic_load(counter, __ATOMIC_RELAXED, __HIP_MEMORY_SCOPE_AGENT) < target)
            __builtin_amdgcn_s_sleep(1);
        __builtin_amdgcn_fence(__ATOMIC_ACQUIRE, "agent");       // invalidate (once)
    }
    __syncthreads();
}

// ---------------------------------------------------------------------------
// Persistent GRU recurrence. 64 blocks x 256 threads.
// Block i: gate cols [i*32, i*32+32), cand cols [i*16, i*16+16).
// Gate weights: pinned in VGPRs. Cand weights: LDS (XOR-swizzled).
// ---------------------------------------------------------------------------
__global__ __launch_bounds__(256, 1) void gru_persistent(
    const unsigned short* __restrict__ WgT,   // [2048][2048] bf16
    const unsigned short* __restrict__ WcT,   // [1024][2048] bf16
    const unsigned short* __restrict__ Xgb,   // [B*T][2048] bf16
    const unsigned short* __restrict__ Xcb,   // [B*T][1024] bf16
    const float* __restrict__ bg,             // [2048]
    const float* __restrict__ bc,             // [1024]
    float* __restrict__ h,                    // [32][1024] f32
    unsigned short* __restrict__ hb,          // [32][1024] bf16
    unsigned short* __restrict__ rhb,         // [32][1024] bf16
    float* __restrict__ ub,                   // [32][1024] f32
    float* __restrict__ out,                  // [B][T][U] f32
    unsigned* __restrict__ bar)
{
    __shared__ float red[4][32][32];              // 16 KB
    __shared__ unsigned short wc_l[16 * 1024];    // 32 KB, XOR-swizzled
    const int tid  = threadIdx.x;
    const int lane = tid & 63;
    const int wave = tid >> 6;
    const int l15  = lane & 15;
    const int kg   = lane >> 4;
    const int blk  = blockIdx.x;
    const int gj0  = blk * 32;
    const int cj0  = blk * 16;
    const int kb   = wave * 256;
    const bool is_r = (gj0 < UU);

    // ---- stage cand recurrent weights into LDS (once), XOR-swizzled ----
    #pragma unroll
    for (int it = 0; it < 8; ++it) {
        int c   = tid + it * 256;        // 2048 chunks of 16 B
        int col = c >> 7;                // 0..15
        int k   = (c & 127) * 8;         // 0..1016
        s8v w = *(const s8v*)(WcT + (size_t)(cj0 + col) * 2048 + 1024 + k);
        *(s8v*)&wc_l[col * 1024 + (k ^ ((col & 7) << 3))] = w;
    }

    // ---- gate recurrent weight B-fragments into registers (once) ----
    s8v bgf[2][8];
    #pragma unroll
    for (int n = 0; n < 2; ++n)
        #pragma unroll
        for (int kk = 0; kk < 8; ++kk)
            bgf[n][kk] = *(const s8v*)(WgT + (size_t)(gj0 + n * 16 + l15) * 2048
                                            + 1024 + kb + kk * 32 + kg * 8);

    // epilogue mapping
    const int eb = tid >> 3;                  // 0..31
    const int eq = tid & 7;                   // 0..7
    const float4 bgv = *(const float4*)(bg + gj0 + eq * 4);
    const float2 bcv = *(const float2*)(bc + cj0 + eq * 2);

    __syncthreads();                          // wc_l ready

    unsigned epoch = 0;
    ushort4 xg = *(const ushort4*)(Xgb + ((size_t)eb * TT + 0) * 2048 + gj0 + eq * 4);

    for (int t = 0; t < TT; ++t) {
        // keep gate weights register-resident (opaque redef each iteration)
        #pragma unroll
        for (int n = 0; n < 2; ++n)
            #pragma unroll
            for (int kk = 0; kk < 8; ++kk)
                asm volatile("" : "+v"(bgf[n][kk]));

        // ================= phase G: gates =================
        float4 hsl;
        if (is_r) hsl = *(const float4*)(h + eb * UU + gj0 + eq * 4);

        s8v a[2][8];
        #pragma unroll
        for (int m = 0; m < 2; ++m)
            #pragma unroll
            for (int kk = 0; kk < 8; ++kk)
                a[m][kk] = *(const s8v*)(hb + (size_t)(m * 16 + l15) * 1024 + kb + kk * 32 + kg * 8);

        f4v acc[2][2];
        #pragma unroll
        for (int m = 0; m < 2; ++m)
            #pragma unroll
            for (int n = 0; n < 2; ++n) acc[m][n] = (f4v){0.f, 0.f, 0.f, 0.f};
        #pragma unroll
        for (int kk = 0; kk < 8; ++kk)
            #pragma unroll
            for (int m = 0; m < 2; ++m)
                #pragma unroll
                for (int n = 0; n < 2; ++n)
                    acc[m][n] = __builtin_amdgcn_mfma_f32_16x16x32_bf16(a[m][kk], bgf[n][kk], acc[m][n], 0, 0, 0);

        #pragma unroll
        for (int m = 0; m < 2; ++m)
            #pragma unroll
            for (int n = 0; n < 2; ++n)
                #pragma unroll
                for (int i = 0; i < 4; ++i)
                    red[wave][m * 16 + kg * 4 + i][n * 16 + l15] = acc[m][n][i];
        __syncthreads();

        f4v pre = *(const f4v*)&red[0][eb][eq * 4];
        #pragma unroll
        for (int w = 1; w < 4; ++w) pre += *(const f4v*)&red[w][eb][eq * 4];
        pre[0] += bf2f(xg.x) + bgv.x;
        pre[1] += bf2f(xg.y) + bgv.y;
        pre[2] += bf2f(xg.z) + bgv.z;
        pre[3] += bf2f(xg.w) + bgv.w;
        float s0 = 1.f / (1.f + __expf(-pre[0]));
        float s1 = 1.f / (1.f + __expf(-pre[1]));
        float s2 = 1.f / (1.f + __expf(-pre[2]));
        float s3 = 1.f / (1.f + __expf(-pre[3]));
        if (is_r) {
            ushort4 o;
            o.x = f2bf(s0 * hsl.x); o.y = f2bf(s1 * hsl.y);
            o.z = f2bf(s2 * hsl.z); o.w = f2bf(s3 * hsl.w);
            *(ushort4*)(rhb + eb * UU + gj0 + eq * 4) = o;
        } else {
            float4 uo = {s0, s1, s2, s3};
            *(float4*)(ub + eb * UU + (gj0 - UU) + eq * 4) = uo;
        }

        // pre-issue C-phase operands that are stable during G
        ushort2 xc = *(const ushort2*)(Xcb + ((size_t)eb * TT + t) * 1024 + cj0 + eq * 2);
        float2 hv  = *(const float2*)(h + eb * UU + cj0 + eq * 2);

        ++epoch;
        grid_barrier(bar, epoch * NBLK, tid);

        // ================= phase C: candidate + update =================
        float2 uv = *(const float2*)(ub + eb * UU + cj0 + eq * 2);

        s8v ac[2][8];
        #pragma unroll
        for (int m = 0; m < 2; ++m)
            #pragma unroll
            for (int kk = 0; kk < 8; ++kk)
                ac[m][kk] = *(const s8v*)(rhb + (size_t)(m * 16 + l15) * 1024 + kb + kk * 32 + kg * 8);

        f4v acc2[2];
        acc2[0] = (f4v){0.f, 0.f, 0.f, 0.f};
        acc2[1] = (f4v){0.f, 0.f, 0.f, 0.f};
        #pragma unroll
        for (int kk = 0; kk < 8; ++kk) {
            s8v bcf = *(const s8v*)&wc_l[l15 * 1024 + ((kb + kk * 32 + kg * 8) ^ ((l15 & 7) << 3))];
            #pragma unroll
            for (int m = 0; m < 2; ++m)
                acc2[m] = __builtin_amdgcn_mfma_f32_16x16x32_bf16(ac[m][kk], bcf, acc2[m], 0, 0, 0);
        }

        float* redc = (float*)red;            // [4][32][16]
        #pragma unroll
        for (int m = 0; m < 2; ++m)
            #pragma unroll
            for (int i = 0; i < 4; ++i)
                redc[((size_t)wave * 32 + m * 16 + kg * 4 + i) * 16 + l15] = acc2[m][i];
        __syncthreads();

        float2 pre2 = *(const float2*)&redc[(0 * 32 + eb) * 16 + eq * 2];
        #pragma unroll
        for (int w = 1; w < 4; ++w) {
            float2 p = *(const float2*)&redc[((size_t)w * 32 + eb) * 16 + eq * 2];
            pre2.x += p.x; pre2.y += p.y;
        }
        float c0 = pre2.x + bf2f(xc.x) + bcv.x;
        float c1 = pre2.y + bf2f(xc.y) + bcv.y;
        c0 = fminf(fmaxf(c0, -15.f), 15.f);
        c1 = fminf(fmaxf(c1, -15.f), 15.f);
        float e0 = __expf(2.f * c0), e1 = __expf(2.f * c1);
        float t0 = (e0 - 1.f) / (e0 + 1.f);
        float t1 = (e1 - 1.f) / (e1 + 1.f);
        float hn0 = uv.x * hv.x + (1.f - uv.x) * t0;
        float hn1 = uv.y * hv.y + (1.f - uv.y) * t1;

        *(float2*)(h + eb * UU + cj0 + eq * 2) = make_float2(hn0, hn1);
        ushort2 hbo; hbo.x = f2bf(hn0); hbo.y = f2bf(hn1);
        *(ushort2*)(hb + eb * UU + cj0 + eq * 2) = hbo;
        *(float2*)(out + ((size_t)eb * TT + t) * UU + cj0 + eq * 2) = make_float2(hn0, hn1);

        // prefetch next step's Xg while others still compute
        if (t + 1 < TT)
            xg = *(const ushort4*)(Xgb + ((size_t)eb * TT + t + 1) * 2048 + gj0 + eq * 4);

        ++epoch;
        if (t + 1 < TT) grid_barrier(bar, epoch * NBLK, tid);
    }
}

// ===========================================================================
// Fallback per-step kernels (round-2, verified) — used only if ws too small.
// ===========================================================================
__global__ __launch_bounds__(256) void gru_gates2(
    const unsigned short* __restrict__ hb, const unsigned short* __restrict__ WgT,
    const unsigned short* __restrict__ Xgb, const float* __restrict__ bg,
    const float* __restrict__ h, unsigned short* __restrict__ rhb,
    float* __restrict__ ubuf, int t)
{
    __shared__ unsigned short hb_l[32][1032];
    __shared__ unsigned short Wl[16][1032];
    __shared__ float red[4][32][16];
    const int tid = threadIdx.x, lane = tid & 63, wave = tid >> 6;
    const int l15 = lane & 15, kg = lane >> 4;
    const int j0 = blockIdx.x * 16;
    #pragma unroll
    for (int it = 0; it < 16; ++it) {
        int c = tid + it * 256; int r = c >> 7, off = (c & 127) * 8;
        *(s8v*)&hb_l[r][off] = *(const s8v*)(hb + (size_t)r * 1024 + off);
    }
    #pragma unroll
    for (int it = 0; it < 8; ++it) {
        int c = tid + it * 256; int r = c >> 7, off = (c & 127) * 8;
        *(s8v*)&Wl[r][off] = *(const s8v*)(WgT + (size_t)(j0 + r) * 2048 + 1024 + off);
    }
    __syncthreads();
    f4v acc0 = (f4v){0.f,0.f,0.f,0.f}, acc1 = (f4v){0.f,0.f,0.f,0.f};
    const int kbase = wave * 256;
    #pragma unroll
    for (int kk = 0; kk < 8; ++kk) {
        int k = kbase + kk * 32 + kg * 8;
        s8v a0 = *(const s8v*)&hb_l[l15][k];
        s8v a1 = *(const s8v*)&hb_l[16 + l15][k];
        s8v b  = *(const s8v*)&Wl[l15][k];
        acc0 = __builtin_amdgcn_mfma_f32_16x16x32_bf16(a0, b, acc0, 0, 0, 0);
        acc1 = __builtin_amdgcn_mfma_f32_16x16x32_bf16(a1, b, acc1, 0, 0, 0);
    }
    #pragma unroll
    for (int i = 0; i < 4; ++i) {
        red[wave][kg * 4 + i][l15] = acc0[i];
        red[wave][16 + kg * 4 + i][l15] = acc1[i];
    }
    __syncthreads();
    for (int e = tid; e < 512; e += 256) {
        int b = e >> 4, col = e & 15;
        int j = j0 + col;
        float pre = red[0][b][col] + red[1][b][col] + red[2][b][col] + red[3][b][col];
        pre += bf2f(Xgb[((size_t)b * TT + t) * 2048 + j]) + bg[j];
        float s = 1.f / (1.f + __expf(-pre));
        if (j < UU) rhb[b * UU + j] = f2bf(s * h[b * UU + j]);
        else        ubuf[b * UU + (j - UU)] = s;
    }
}

__global__ __launch_bounds__(256) void gru_cand2(
    const unsigned short* __restrict__ rhb, const unsigned short* __restrict__ WcT,
    const unsigned short* __restrict__ Xcb, const float* __restrict__ bc,
    const float* __restrict__ ubuf, float* __restrict__ h,
    unsigned short* __restrict__ hb, float* __restrict__ out, int t)
{
    __shared__ unsigned short rh_l[32][1032];
    __shared__ unsigned short Wl[16][1032];
    __shared__ float red[4][32][16];
    const int tid = threadIdx.x, lane = tid & 63, wave = tid >> 6;
    const int l15 = lane & 15, kg = lane >> 4;
    const int j0 = blockIdx.x * 16;
    #pragma unroll
    for (int it = 0; it < 16; ++it) {
        int c = tid + it * 256; int r = c >> 7, off = (c & 127) * 8;
        *(s8v*)&rh_l[r][off] = *(const s8v*)(rhb + (size_t)r * 1024 + off);
    }
    #pragma unroll
    for (int it = 0; it < 8; ++it) {
        int c = tid + it * 256; int r = c >> 7, off = (c & 127) * 8;
        *(s8v*)&Wl[r][off] = *(const s8v*)(WcT + (size_t)(j0 + r) * 2048 + 1024 + off);
    }
    __syncthreads();
    f4v acc0 = (f4v){0.f,0.f,0.f,0.f}, acc1 = (f4v){0.f,0.f,0.f,0.f};
    const int kbase = wave * 256;
    #pragma unroll
    for (int kk = 0; kk < 8; ++kk) {
        int k = kbase + kk * 32 + kg * 8;
        s8v a0 = *(const s8v*)&rh_l[l15][k];
        s8v a1 = *(const s8v*)&rh_l[16 + l15][k];
        s8v b  = *(const s8v*)&Wl[l15][k];
        acc0 = __builtin_amdgcn_mfma_f32_16x16x32_bf16(a0, b, acc0, 0, 0, 0);
        acc1 = __builtin_amdgcn_mfma_f32_16x16x32_bf16(a1, b, acc1, 0, 0, 0);
    }
    #pragma unroll
    for (int i = 0; i < 4; ++i) {
        red[wave][kg * 4 + i][l15] = acc0[i];
        red[wave][16 + kg * 4 + i][l15] = acc1[i];
    }
    __syncthreads();
    for (int e = tid; e < 512; e += 256) {
        int b = e >> 4, col = e & 15;
        int j = j0 + col;
        float pre = red[0][b][col] + red[1][b][col] + red[2][b][col] + red[3][b][col];
        pre += bf2f(Xcb[((size_t)b * TT + t) * 1024 + j]) + bc[j];
        float cv = tanhf(pre);
        float u  = ubuf[b * UU + j];
        float hv = h[b * UU + j];
        float hn = u * hv + (1.f - u) * cv;
        h[b * UU + j]  = hn;
        hb[b * UU + j] = f2bf(hn);
        out[((size_t)b * TT + t) * UU + j] = hn;
    }
}

// ===========================================================================
extern "C" void kernel_launch(void* const* d_in, const int* in_sizes, int n_in,
                              void* d_out, int out_size, void* d_ws, size_t ws_size,
                              hipStream_t stream) {
    const float* x  = (const float*)d_in[0];
    const float* Wg = (const float*)d_in[1];
    const float* bg = (const float*)d_in[2];
    const float* Wc = (const float*)d_in[3];
    const float* bc = (const float*)d_in[4];
    float* out = (float*)d_out;

    const size_t XB_B  = (size_t)BB * TT * FF * 2;
    const size_t WGT_B = (size_t)2 * UU * (FF + UU) * 2;
    const size_t WCT_B = (size_t)UU * (FF + UU) * 2;
    const size_t XG_B  = (size_t)BB * TT * 2 * UU * 2;
    const size_t XC_B  = (size_t)BB * TT * UU * 2;
    const size_t H_B   = (size_t)BB * UU * 4;
    const size_t HB_B  = (size_t)BB * UU * 2;
    const size_t BAR_B = 256;
    const size_t NEED  = XB_B + WGT_B + WCT_B + XG_B + XC_B + H_B + HB_B * 2 + H_B + BAR_B;

    char* p = (char*)d_ws;
    unsigned short* xb  = (unsigned short*)p;            p += XB_B;
    unsigned short* WgT = (unsigned short*)p;            p += WGT_B;
    unsigned short* WcT = (unsigned short*)p;            p += WCT_B;
    unsigned short* Xgb = (unsigned short*)p;            p += XG_B;
    unsigned short* Xcb = (unsigned short*)p;            p += XC_B;
    float*          h   = (float*)p;                     p += H_B;
    unsigned short* hb  = (unsigned short*)p;            p += HB_B;
    unsigned short* rhb = (unsigned short*)p;            p += HB_B;
    float*          ub  = (float*)p;                     p += H_B;
    unsigned*       bar = (unsigned*)p;                  p += BAR_B;

    // ---- one-time prep ----
    cvt_bf16<<<(BB * TT * FF / 4 + 255) / 256, 256, 0, stream>>>(x, xb, BB * TT * FF / 4);
    transpose_bf16<FF + UU, 2 * UU><<<dim3(64, 64), dim3(32, 8), 0, stream>>>(Wg, WgT);
    transpose_bf16<FF + UU, UU>    <<<dim3(32, 64), dim3(32, 8), 0, stream>>>(Wc, WcT);
    gemm_xproj<<<dim3(2 * UU / 128, BB * TT / 128), 256, 0, stream>>>(xb, WgT, Xgb, 2 * UU);
    gemm_xproj<<<dim3(UU / 128,     BB * TT / 128), 256, 0, stream>>>(xb, WcT, Xcb, UU);
    hipMemsetAsync(h,   0, H_B,   stream);
    hipMemsetAsync(hb,  0, HB_B,  stream);
    hipMemsetAsync(bar, 0, BAR_B, stream);

    if (ws_size >= NEED) {
        gru_persistent<<<NBLK, 256, 0, stream>>>(WgT, WcT, Xgb, Xcb, bg, bc,
                                                 h, hb, rhb, ub, out, bar);
    } else {
        for (int t = 0; t < TT; ++t) {
            gru_gates2<<<128, 256, 0, stream>>>(hb, WgT, Xgb, bg, h, rhb, ub, t);
            gru_cand2 <<< 64, 256, 0, stream>>>(rhb, WcT, Xcb, bc, ub, h, hb, out, t);
        }
    }
}

// Round 5
// 4773.636 us; speedup vs baseline: 2.0304x; 1.6210x over previous
//
#include <hip/hip_runtime.h>
#include <math.h>

#define BB 32
#define TT 512
#define FF 1024
#define UU 1024
#define NBLK 64

typedef __attribute__((ext_vector_type(8))) short s8v;    // 8 x bf16 (4 VGPR)
typedef __attribute__((ext_vector_type(4))) float f4v;    // 4 x f32
typedef __attribute__((ext_vector_type(2))) float f2v;    // 2 x f32
typedef __attribute__((ext_vector_type(2))) unsigned int u2v;

static __device__ __forceinline__ unsigned short f2bf(float f) {
    unsigned int u = __builtin_bit_cast(unsigned int, f);
    u += 0x7fff + ((u >> 16) & 1);          // RNE
    return (unsigned short)(u >> 16);
}
static __device__ __forceinline__ float bf2f(unsigned short b) {
    unsigned int u = ((unsigned int)b) << 16;
    return __builtin_bit_cast(float, u);
}

// ---- device-coherent (agent-scope) accesses: bypass non-coherent L1/L2 ----
static __device__ __forceinline__ s8v ld_b128_sc(const void* p) {
    s8v r;
    asm volatile("global_load_dwordx4 %0, %1, off sc0 sc1" : "=v"(r) : "v"(p));
    return r;
}
static __device__ __forceinline__ f4v ld_f128_sc(const void* p) {
    f4v r;
    asm volatile("global_load_dwordx4 %0, %1, off sc0 sc1" : "=v"(r) : "v"(p));
    return r;
}
static __device__ __forceinline__ f2v ld_f64_sc(const void* p) {
    f2v r;
    asm volatile("global_load_dwordx2 %0, %1, off sc0 sc1" : "=v"(r) : "v"(p));
    return r;
}
static __device__ __forceinline__ void st_b128_sc(void* p, f4v v) {
    asm volatile("global_store_dwordx4 %0, %1, off sc0 sc1" :: "v"(p), "v"(v));
}
static __device__ __forceinline__ void st_b64_sc(void* p, u2v v) {
    asm volatile("global_store_dwordx2 %0, %1, off sc0 sc1" :: "v"(p), "v"(v));
}
static __device__ __forceinline__ void st_f64_sc(void* p, f2v v) {
    asm volatile("global_store_dwordx2 %0, %1, off sc0 sc1" :: "v"(p), "v"(v));
}
static __device__ __forceinline__ void st_b32_sc(void* p, unsigned int v) {
    asm volatile("global_store_dword %0, %1, off sc0 sc1" :: "v"(p), "v"(v));
}
static __device__ __forceinline__ void vm_drain_schedfence() {
    asm volatile("s_waitcnt vmcnt(0)" ::: "memory");
    __builtin_amdgcn_sched_barrier(0);
}

// ---------------------------------------------------------------------------
__global__ __launch_bounds__(256) void cvt_bf16(
    const float* __restrict__ in, unsigned short* __restrict__ out, int n4)
{
    int i = blockIdx.x * 256 + threadIdx.x;
    if (i < n4) {
        float4 v = ((const float4*)in)[i];
        ushort4 o;
        o.x = f2bf(v.x); o.y = f2bf(v.y); o.z = f2bf(v.z); o.w = f2bf(v.w);
        ((ushort4*)out)[i] = o;
    }
}

// ---------------------------------------------------------------------------
template<int ROWS, int COLS>
__global__ __launch_bounds__(256) void transpose_bf16(
    const float* __restrict__ W, unsigned short* __restrict__ WT)
{
    __shared__ float tl[32][33];
    const int tx = threadIdx.x, ty = threadIdx.y;   // block (32, 8)
    const int bx = blockIdx.x, by = blockIdx.y;
    #pragma unroll
    for (int i = 0; i < 4; ++i) {
        int r = by * 32 + ty + i * 8;
        int c = bx * 32 + tx;
        tl[ty + i * 8][tx] = W[(size_t)r * COLS + c];
    }
    __syncthreads();
    #pragma unroll
    for (int i = 0; i < 4; ++i) {
        int n = bx * 32 + ty + i * 8;
        int k = by * 32 + tx;
        WT[(size_t)n * ROWS + k] = f2bf(tl[tx][ty + i * 8]);
    }
}

// ---------------------------------------------------------------------------
__global__ __launch_bounds__(256) void gemm_xproj(
    const unsigned short* __restrict__ A,    // [M][1024]
    const unsigned short* __restrict__ BT,   // [N][2048]
    unsigned short* __restrict__ C,          // [M][N]
    int N)
{
    __shared__ unsigned short Al[128][72];
    __shared__ unsigned short Bl[128][72];
    const int tid  = threadIdx.x;
    const int lane = tid & 63;
    const int wave = tid >> 6;
    const int l15  = lane & 15;
    const int kg   = lane >> 4;
    const int m0   = blockIdx.y * 128;
    const int n0   = blockIdx.x * 128;
    const int rowOff = (wave >> 1) * 64;
    const int colOff = (wave & 1) * 64;

    f4v acc[4][4];
    #pragma unroll
    for (int m = 0; m < 4; ++m)
        #pragma unroll
        for (int n = 0; n < 4; ++n) acc[m][n] = (f4v){0.f, 0.f, 0.f, 0.f};

    for (int k0 = 0; k0 < 1024; k0 += 64) {
        #pragma unroll
        for (int it = 0; it < 4; ++it) {
            int c = tid + it * 256;
            int r = c >> 3, off = (c & 7) * 8;
            *(s8v*)&Al[r][off] = *(const s8v*)(A + (size_t)(m0 + r) * 1024 + k0 + off);
            *(s8v*)&Bl[r][off] = *(const s8v*)(BT + (size_t)(n0 + r) * 2048 + k0 + off);
        }
        __syncthreads();
        #pragma unroll
        for (int ks = 0; ks < 2; ++ks) {
            s8v a[4], b[4];
            #pragma unroll
            for (int m = 0; m < 4; ++m)
                a[m] = *(const s8v*)&Al[rowOff + m * 16 + l15][ks * 32 + kg * 8];
            #pragma unroll
            for (int n = 0; n < 4; ++n)
                b[n] = *(const s8v*)&Bl[colOff + n * 16 + l15][ks * 32 + kg * 8];
            #pragma unroll
            for (int m = 0; m < 4; ++m)
                #pragma unroll
                for (int n = 0; n < 4; ++n)
                    acc[m][n] = __builtin_amdgcn_mfma_f32_16x16x32_bf16(a[m], b[n], acc[m][n], 0, 0, 0);
        }
        __syncthreads();
    }
    #pragma unroll
    for (int m = 0; m < 4; ++m)
        #pragma unroll
        for (int n = 0; n < 4; ++n)
            #pragma unroll
            for (int i = 0; i < 4; ++i) {
                int row = m0 + rowOff + m * 16 + kg * 4 + i;
                int col = n0 + colOff + n * 16 + l15;
                C[(size_t)row * N + col] = f2bf(acc[m][n][i]);
            }
}

// ---------------------------------------------------------------------------
// Fence-free grid barrier. All state data moves with sc0/sc1 coherent ops,
// so no cache maintenance is required here. vmcnt drain orders the sc1
// stores before the arrival signal. Monotonic counter, relaxed spin.
// ---------------------------------------------------------------------------
__device__ __forceinline__ void grid_barrier(unsigned* counter, unsigned target, int tid)
{
    asm volatile("s_waitcnt vmcnt(0)" ::: "memory");   // stores visible before arrive
    __syncthreads();
    if (tid == 0) {
        __hip_atomic_fetch_add(counter, 1u, __ATOMIC_RELAXED, __HIP_MEMORY_SCOPE_AGENT);
        while (__hip_atomic_load(counter, __ATOMIC_RELAXED, __HIP_MEMORY_SCOPE_AGENT) < target)
            __builtin_amdgcn_s_sleep(1);
    }
    __syncthreads();
}

// ---------------------------------------------------------------------------
// Persistent GRU recurrence. 64 blocks x 256 threads.
// Block i: gate cols [i*32, i*32+32), cand cols [i*16, i*16+16).
// Mutable state (hb/rhb/ub/h) via sc0sc1 coherent ops; weights/Xg/Xc via
// normal cached loads (L2 stays warm — no fences ever invalidate it).
// ---------------------------------------------------------------------------
__global__ __launch_bounds__(256, 1) void gru_persistent(
    const unsigned short* __restrict__ WgT,   // [2048][2048] bf16
    const unsigned short* __restrict__ WcT,   // [1024][2048] bf16
    const unsigned short* __restrict__ Xgb,   // [B*T][2048] bf16
    const unsigned short* __restrict__ Xcb,   // [B*T][1024] bf16
    const float* __restrict__ bg,             // [2048]
    const float* __restrict__ bc,             // [1024]
    float* __restrict__ h,                    // [32][1024] f32
    unsigned short* __restrict__ hb,          // [32][1024] bf16
    unsigned short* __restrict__ rhb,         // [32][1024] bf16
    float* __restrict__ ub,                   // [32][1024] f32
    float* __restrict__ out,                  // [B][T][U] f32
    unsigned* __restrict__ bar)
{
    __shared__ float red[4][32][32];              // 16 KB
    __shared__ unsigned short wc_l[16 * 1024];    // 32 KB, XOR-swizzled
    const int tid  = threadIdx.x;
    const int lane = tid & 63;
    const int wave = tid >> 6;
    const int l15  = lane & 15;
    const int kg   = lane >> 4;
    const int blk  = blockIdx.x;
    const int gj0  = blk * 32;
    const int cj0  = blk * 16;
    const int kb   = wave * 256;
    const bool is_r = (gj0 < UU);

    // ---- stage cand recurrent weights into LDS (once), XOR-swizzled ----
    #pragma unroll
    for (int it = 0; it < 8; ++it) {
        int c   = tid + it * 256;        // 2048 chunks of 16 B
        int col = c >> 7;                // 0..15
        int k   = (c & 127) * 8;         // 0..1016
        s8v w = *(const s8v*)(WcT + (size_t)(cj0 + col) * 2048 + 1024 + k);
        *(s8v*)&wc_l[col * 1024 + (k ^ ((col & 7) << 3))] = w;
    }

    // ---- gate recurrent weight B-fragments (compiler may re-load from L2) ----
    s8v bgf[2][8];
    #pragma unroll
    for (int n = 0; n < 2; ++n)
        #pragma unroll
        for (int kk = 0; kk < 8; ++kk)
            bgf[n][kk] = *(const s8v*)(WgT + (size_t)(gj0 + n * 16 + l15) * 2048
                                            + 1024 + kb + kk * 32 + kg * 8);

    // epilogue mapping
    const int eb = tid >> 3;                  // 0..31
    const int eq = tid & 7;                   // 0..7
    const float4 bgv = *(const float4*)(bg + gj0 + eq * 4);
    const float2 bcv = *(const float2*)(bc + cj0 + eq * 2);

    __syncthreads();                          // wc_l ready

    unsigned epoch = 0;
    ushort4 xg = *(const ushort4*)(Xgb + ((size_t)eb * TT + 0) * 2048 + gj0 + eq * 4);

    for (int t = 0; t < TT; ++t) {
        // ================= phase G: gates =================
        f4v hsl = (f4v){0.f,0.f,0.f,0.f};
        if (is_r) hsl = ld_f128_sc(h + eb * UU + gj0 + eq * 4);

        s8v a[2][8];
        #pragma unroll
        for (int m = 0; m < 2; ++m)
            #pragma unroll
            for (int kk = 0; kk < 8; ++kk)
                a[m][kk] = ld_b128_sc(hb + (size_t)(m * 16 + l15) * 1024 + kb + kk * 32 + kg * 8);
        vm_drain_schedfence();

        f4v acc[2][2];
        #pragma unroll
        for (int m = 0; m < 2; ++m)
            #pragma unroll
            for (int n = 0; n < 2; ++n) acc[m][n] = (f4v){0.f, 0.f, 0.f, 0.f};
        #pragma unroll
        for (int kk = 0; kk < 8; ++kk)
            #pragma unroll
            for (int m = 0; m < 2; ++m)
                #pragma unroll
                for (int n = 0; n < 2; ++n)
                    acc[m][n] = __builtin_amdgcn_mfma_f32_16x16x32_bf16(a[m][kk], bgf[n][kk], acc[m][n], 0, 0, 0);

        #pragma unroll
        for (int m = 0; m < 2; ++m)
            #pragma unroll
            for (int n = 0; n < 2; ++n)
                #pragma unroll
                for (int i = 0; i < 4; ++i)
                    red[wave][m * 16 + kg * 4 + i][n * 16 + l15] = acc[m][n][i];
        __syncthreads();

        f4v pre = *(const f4v*)&red[0][eb][eq * 4];
        #pragma unroll
        for (int w = 1; w < 4; ++w) pre += *(const f4v*)&red[w][eb][eq * 4];
        pre[0] += bf2f(xg.x) + bgv.x;
        pre[1] += bf2f(xg.y) + bgv.y;
        pre[2] += bf2f(xg.z) + bgv.z;
        pre[3] += bf2f(xg.w) + bgv.w;
        float s0 = 1.f / (1.f + __expf(-pre[0]));
        float s1 = 1.f / (1.f + __expf(-pre[1]));
        float s2 = 1.f / (1.f + __expf(-pre[2]));
        float s3 = 1.f / (1.f + __expf(-pre[3]));
        if (is_r) {
            unsigned int lo = (unsigned int)f2bf(s0 * hsl[0]) | ((unsigned int)f2bf(s1 * hsl[1]) << 16);
            unsigned int hi = (unsigned int)f2bf(s2 * hsl[2]) | ((unsigned int)f2bf(s3 * hsl[3]) << 16);
            st_b64_sc(rhb + eb * UU + gj0 + eq * 4, (u2v){lo, hi});
        } else {
            st_b128_sc(ub + eb * UU + (gj0 - UU) + eq * 4, (f4v){s0, s1, s2, s3});
        }

        // pre-issue C-phase operands that are stable during G
        ushort2 xc = *(const ushort2*)(Xcb + ((size_t)eb * TT + t) * 1024 + cj0 + eq * 2);
        f2v hv = ld_f64_sc(h + eb * UU + cj0 + eq * 2);   // own block's cols: stable in G

        ++epoch;
        grid_barrier(bar, epoch * NBLK, tid);

        // ================= phase C: candidate + update =================
        f2v uv = ld_f64_sc(ub + eb * UU + cj0 + eq * 2);

        s8v ac[2][8];
        #pragma unroll
        for (int m = 0; m < 2; ++m)
            #pragma unroll
            for (int kk = 0; kk < 8; ++kk)
                ac[m][kk] = ld_b128_sc(rhb + (size_t)(m * 16 + l15) * 1024 + kb + kk * 32 + kg * 8);
        vm_drain_schedfence();

        f4v acc2[2];
        acc2[0] = (f4v){0.f, 0.f, 0.f, 0.f};
        acc2[1] = (f4v){0.f, 0.f, 0.f, 0.f};
        #pragma unroll
        for (int kk = 0; kk < 8; ++kk) {
            s8v bcf = *(const s8v*)&wc_l[l15 * 1024 + ((kb + kk * 32 + kg * 8) ^ ((l15 & 7) << 3))];
            #pragma unroll
            for (int m = 0; m < 2; ++m)
                acc2[m] = __builtin_amdgcn_mfma_f32_16x16x32_bf16(ac[m][kk], bcf, acc2[m], 0, 0, 0);
        }

        float* redc = (float*)red;            // [4][32][16]
        #pragma unroll
        for (int m = 0; m < 2; ++m)
            #pragma unroll
            for (int i = 0; i < 4; ++i)
                redc[((size_t)wave * 32 + m * 16 + kg * 4 + i) * 16 + l15] = acc2[m][i];
        __syncthreads();

        float2 pre2 = *(const float2*)&redc[(0 * 32 + eb) * 16 + eq * 2];
        #pragma unroll
        for (int w = 1; w < 4; ++w) {
            float2 p = *(const float2*)&redc[((size_t)w * 32 + eb) * 16 + eq * 2];
            pre2.x += p.x; pre2.y += p.y;
        }
        float c0 = pre2.x + bf2f(xc.x) + bcv.x;
        float c1 = pre2.y + bf2f(xc.y) + bcv.y;
        c0 = fminf(fmaxf(c0, -15.f), 15.f);
        c1 = fminf(fmaxf(c1, -15.f), 15.f);
        float e0 = __expf(2.f * c0), e1 = __expf(2.f * c1);
        float t0 = (e0 - 1.f) / (e0 + 1.f);
        float t1 = (e1 - 1.f) / (e1 + 1.f);
        float hn0 = uv[0] * hv[0] + (1.f - uv[0]) * t0;
        float hn1 = uv[1] * hv[1] + (1.f - uv[1]) * t1;

        st_f64_sc(h + eb * UU + cj0 + eq * 2, (f2v){hn0, hn1});
        st_b32_sc(hb + eb * UU + cj0 + eq * 2,
                  (unsigned int)f2bf(hn0) | ((unsigned int)f2bf(hn1) << 16));
        *(float2*)(out + ((size_t)eb * TT + t) * UU + cj0 + eq * 2) = make_float2(hn0, hn1);

        // prefetch next step's Xg while others still compute
        if (t + 1 < TT)
            xg = *(const ushort4*)(Xgb + ((size_t)eb * TT + t + 1) * 2048 + gj0 + eq * 4);

        ++epoch;
        if (t + 1 < TT) grid_barrier(bar, epoch * NBLK, tid);
    }
}

// ===========================================================================
// Fallback per-step kernels (round-2, verified) — used only if ws too small.
// ===========================================================================
__global__ __launch_bounds__(256) void gru_gates2(
    const unsigned short* __restrict__ hb, const unsigned short* __restrict__ WgT,
    const unsigned short* __restrict__ Xgb, const float* __restrict__ bg,
    const float* __restrict__ h, unsigned short* __restrict__ rhb,
    float* __restrict__ ubuf, int t)
{
    __shared__ unsigned short hb_l[32][1032];
    __shared__ unsigned short Wl[16][1032];
    __shared__ float red[4][32][16];
    const int tid = threadIdx.x, lane = tid & 63, wave = tid >> 6;
    const int l15 = lane & 15, kg = lane >> 4;
    const int j0 = blockIdx.x * 16;
    #pragma unroll
    for (int it = 0; it < 16; ++it) {
        int c = tid + it * 256; int r = c >> 7, off = (c & 127) * 8;
        *(s8v*)&hb_l[r][off] = *(const s8v*)(hb + (size_t)r * 1024 + off);
    }
    #pragma unroll
    for (int it = 0; it < 8; ++it) {
        int c = tid + it * 256; int r = c >> 7, off = (c & 127) * 8;
        *(s8v*)&Wl[r][off] = *(const s8v*)(WgT + (size_t)(j0 + r) * 2048 + 1024 + off);
    }
    __syncthreads();
    f4v acc0 = (f4v){0.f,0.f,0.f,0.f}, acc1 = (f4v){0.f,0.f,0.f,0.f};
    const int kbase = wave * 256;
    #pragma unroll
    for (int kk = 0; kk < 8; ++kk) {
        int k = kbase + kk * 32 + kg * 8;
        s8v a0 = *(const s8v*)&hb_l[l15][k];
        s8v a1 = *(const s8v*)&hb_l[16 + l15][k];
        s8v b  = *(const s8v*)&Wl[l15][k];
        acc0 = __builtin_amdgcn_mfma_f32_16x16x32_bf16(a0, b, acc0, 0, 0, 0);
        acc1 = __builtin_amdgcn_mfma_f32_16x16x32_bf16(a1, b, acc1, 0, 0, 0);
    }
    #pragma unroll
    for (int i = 0; i < 4; ++i) {
        red[wave][kg * 4 + i][l15] = acc0[i];
        red[wave][16 + kg * 4 + i][l15] = acc1[i];
    }
    __syncthreads();
    for (int e = tid; e < 512; e += 256) {
        int b = e >> 4, col = e & 15;
        int j = j0 + col;
        float pre = red[0][b][col] + red[1][b][col] + red[2][b][col] + red[3][b][col];
        pre += bf2f(Xgb[((size_t)b * TT + t) * 2048 + j]) + bg[j];
        float s = 1.f / (1.f + __expf(-pre));
        if (j < UU) rhb[b * UU + j] = f2bf(s * h[b * UU + j]);
        else        ubuf[b * UU + (j - UU)] = s;
    }
}

__global__ __launch_bounds__(256) void gru_cand2(
    const unsigned short* __restrict__ rhb, const unsigned short* __restrict__ WcT,
    const unsigned short* __restrict__ Xcb, const float* __restrict__ bc,
    const float* __restrict__ ubuf, float* __restrict__ h,
    unsigned short* __restrict__ hb, float* __restrict__ out, int t)
{
    __shared__ unsigned short rh_l[32][1032];
    __shared__ unsigned short Wl[16][1032];
    __shared__ float red[4][32][16];
    const int tid = threadIdx.x, lane = tid & 63, wave = tid >> 6;
    const int l15 = lane & 15, kg = lane >> 4;
    const int j0 = blockIdx.x * 16;
    #pragma unroll
    for (int it = 0; it < 16; ++it) {
        int c = tid + it * 256; int r = c >> 7, off = (c & 127) * 8;
        *(s8v*)&rh_l[r][off] = *(const s8v*)(rhb + (size_t)r * 1024 + off);
    }
    #pragma unroll
    for (int it = 0; it < 8; ++it) {
        int c = tid + it * 256; int r = c >> 7, off = (c & 127) * 8;
        *(s8v*)&Wl[r][off] = *(const s8v*)(WcT + (size_t)(j0 + r) * 2048 + 1024 + off);
    }
    __syncthreads();
    f4v acc0 = (f4v){0.f,0.f,0.f,0.f}, acc1 = (f4v){0.f,0.f,0.f,0.f};
    const int kbase = wave * 256;
    #pragma unroll
    for (int kk = 0; kk < 8; ++kk) {
        int k = kbase + kk * 32 + kg * 8;
        s8v a0 = *(const s8v*)&rh_l[l15][k];
        s8v a1 = *(const s8v*)&rh_l[16 + l15][k];
        s8v b  = *(const s8v*)&Wl[l15][k];
        acc0 = __builtin_amdgcn_mfma_f32_16x16x32_bf16(a0, b, acc0, 0, 0, 0);
        acc1 = __builtin_amdgcn_mfma_f32_16x16x32_bf16(a1, b, acc1, 0, 0, 0);
    }
    #pragma unroll
    for (int i = 0; i < 4; ++i) {
        red[wave][kg * 4 + i][l15] = acc0[i];
        red[wave][16 + kg * 4 + i][l15] = acc1[i];
    }
    __syncthreads();
    for (int e = tid; e < 512; e += 256) {
        int b = e >> 4, col = e & 15;
        int j = j0 + col;
        float pre = red[0][b][col] + red[1][b][col] + red[2][b][col] + red[3][b][col];
        pre += bf2f(Xcb[((size_t)b * TT + t) * 1024 + j]) + bc[j];
        float cv = tanhf(pre);
        float u  = ubuf[b * UU + j];
        float hv = h[b * UU + j];
        float hn = u * hv + (1.f - u) * cv;
        h[b * UU + j]  = hn;
        hb[b * UU + j] = f2bf(hn);
        out[((size_t)b * TT + t) * UU + j] = hn;
    }
}

// ===========================================================================
extern "C" void kernel_launch(void* const* d_in, const int* in_sizes, int n_in,
                              void* d_out, int out_size, void* d_ws, size_t ws_size,
                              hipStream_t stream) {
    const float* x  = (const float*)d_in[0];
    const float* Wg = (const float*)d_in[1];
    const float* bg = (const float*)d_in[2];
    const float* Wc = (const float*)d_in[3];
    const float* bc = (const float*)d_in[4];
    float* out = (float*)d_out;

    const size_t XB_B  = (size_t)BB * TT * FF * 2;
    const size_t WGT_B = (size_t)2 * UU * (FF + UU) * 2;
    const size_t WCT_B = (size_t)UU * (FF + UU) * 2;
    const size_t XG_B  = (size_t)BB * TT * 2 * UU * 2;
    const size_t XC_B  = (size_t)BB * TT * UU * 2;
    const size_t H_B   = (size_t)BB * UU * 4;
    const size_t HB_B  = (size_t)BB * UU * 2;
    const size_t BAR_B = 256;
    const size_t NEED  = XB_B + WGT_B + WCT_B + XG_B + XC_B + H_B + HB_B * 2 + H_B + BAR_B;

    char* p = (char*)d_ws;
    unsigned short* xb  = (unsigned short*)p;            p += XB_B;
    unsigned short* WgT = (unsigned short*)p;            p += WGT_B;
    unsigned short* WcT = (unsigned short*)p;            p += WCT_B;
    unsigned short* Xgb = (unsigned short*)p;            p += XG_B;
    unsigned short* Xcb = (unsigned short*)p;            p += XC_B;
    float*          h   = (float*)p;                     p += H_B;
    unsigned short* hb  = (unsigned short*)p;            p += HB_B;
    unsigned short* rhb = (unsigned short*)p;            p += HB_B;
    float*          ub  = (float*)p;                     p += H_B;
    unsigned*       bar = (unsigned*)p;                  p += BAR_B;

    // ---- one-time prep ----
    cvt_bf16<<<(BB * TT * FF / 4 + 255) / 256, 256, 0, stream>>>(x, xb, BB * TT * FF / 4);
    transpose_bf16<FF + UU, 2 * UU><<<dim3(64, 64), dim3(32, 8), 0, stream>>>(Wg, WgT);
    transpose_bf16<FF + UU, UU>    <<<dim3(32, 64), dim3(32, 8), 0, stream>>>(Wc, WcT);
    gemm_xproj<<<dim3(2 * UU / 128, BB * TT / 128), 256, 0, stream>>>(xb, WgT, Xgb, 2 * UU);
    gemm_xproj<<<dim3(UU / 128,     BB * TT / 128), 256, 0, stream>>>(xb, WcT, Xcb, UU);
    hipMemsetAsync(h,   0, H_B,   stream);
    hipMemsetAsync(hb,  0, HB_B,  stream);
    hipMemsetAsync(bar, 0, BAR_B, stream);

    if (ws_size >= NEED) {
        gru_persistent<<<NBLK, 256, 0, stream>>>(WgT, WcT, Xgb, Xcb, bg, bc,
                                                 h, hb, rhb, ub, out, bar);
    } else {
        for (int t = 0; t < TT; ++t) {
            gru_gates2<<<128, 256, 0, stream>>>(hb, WgT, Xgb, bg, h, rhb, ub, t);
            gru_cand2 <<< 64, 256, 0, stream>>>(rhb, WcT, Xcb, bc, ub, h, hb, out, t);
        }
    }
}